// Round 7
// baseline (406.341 us; speedup 1.0000x reference)
//
#include <hip/hip_runtime.h>
#include <hip/hip_bf16.h>

// ---------------------------------------------------------------------------
// GraphSAGE forward on MI355X — round 10.
// Post-mortem of round 9: column-split aggregate was neutral-to-worse (12.8MB
// still >> 4MB L2/XCD; per-XCD line duplication is the structural floor) ->
// reverted to round-8 aggregate. NEW finding: scatter2 is ~50us with 53.5MB
// WRITE for 6.4MB logical — 8x sector amplification because each node's
// edges scatter-write from ALL XCDs (sectors never coalesce in one L2).
// Change:
//   * scatter3: (chunk c, slice s) blocks with c = bid%8 -> all writers of
//     chunk c's 800KB esrc window land on ONE XCD (observed round-robin
//     bid->XCD mapping; perf heuristic only). Writes coalesce in that L2.
//     counts16 access becomes block-local (25KB). dst/src/rank re-read 8x
//     but pure streaming, L3-resident.
// ---------------------------------------------------------------------------

typedef __attribute__((ext_vector_type(8))) short short8v;   // 8 x bf16 (4 VGPRs)
typedef __attribute__((ext_vector_type(4))) float f32x4;

#define RK_CH 12544   // nodes per dst-chunk (50,176 B LDS histogram)
#define RK_NS 64      // edge slices

__device__ __forceinline__ unsigned short f2bf(float f) {
    __hip_bfloat16 h = __float2bfloat16(f);
    return *reinterpret_cast<unsigned short*>(&h);
}
__device__ __forceinline__ float bf_lo(unsigned u) { return __uint_as_float(u << 16); }
__device__ __forceinline__ float bf_hi(unsigned u) { return __uint_as_float(u & 0xffff0000u); }
__device__ __forceinline__ unsigned packbf(float lo, float hi) {
    return ((unsigned)f2bf(hi) << 16) | f2bf(lo);
}

// ---------------- CSR build (atomic-free) ----------------

__launch_bounds__(256)
__global__ void rank_hist_kernel(const int* __restrict__ dst,
                                 unsigned short* __restrict__ rank16,
                                 unsigned short* __restrict__ counts16,
                                 int nE, int nChunk, int es) {
    __shared__ unsigned cnt[RK_CH];
    int s = blockIdx.x / nChunk;   // consecutive blocks share the dst slice
    int c = blockIdx.x % nChunk;
    int lo = c * RK_CH;
    for (int i = threadIdx.x; i < RK_CH; i += 256) cnt[i] = 0u;
    __syncthreads();

    int ebeg = s * es;
    int eend = ebeg + es; if (eend > nE) eend = nE;

    if (ebeg < eend) {
        if ((((size_t)dst) & 15) == 0) {   // es is a multiple of 4 -> slice base aligned
            int nvec = (eend - ebeg) >> 2;
            for (int g = threadIdx.x; g < nvec; g += 256) {
                int e = ebeg + g * 4;
                int4 d4 = *(const int4*)&dst[e];
                unsigned dc;
                dc = (unsigned)(d4.x - lo);
                if (dc < RK_CH) rank16[e]     = (unsigned short)atomicAdd(&cnt[dc], 1u);
                dc = (unsigned)(d4.y - lo);
                if (dc < RK_CH) rank16[e + 1] = (unsigned short)atomicAdd(&cnt[dc], 1u);
                dc = (unsigned)(d4.z - lo);
                if (dc < RK_CH) rank16[e + 2] = (unsigned short)atomicAdd(&cnt[dc], 1u);
                dc = (unsigned)(d4.w - lo);
                if (dc < RK_CH) rank16[e + 3] = (unsigned short)atomicAdd(&cnt[dc], 1u);
            }
            for (int e = ebeg + (nvec << 2) + threadIdx.x; e < eend; e += 256) {
                unsigned dc = (unsigned)(dst[e] - lo);
                if (dc < RK_CH) rank16[e] = (unsigned short)atomicAdd(&cnt[dc], 1u);
            }
        } else {
            for (int e = ebeg + threadIdx.x; e < eend; e += 256) {
                unsigned dc = (unsigned)(dst[e] - lo);
                if (dc < RK_CH) rank16[e] = (unsigned short)atomicAdd(&cnt[dc], 1u);
            }
        }
    }
    __syncthreads();
    size_t base = ((size_t)(c * RK_NS + s)) * RK_CH;
    for (int i = threadIdx.x; i < RK_CH; i += 256)
        counts16[base + i] = (unsigned short)cnt[i];
}

__global__ void seg_offsets_kernel(unsigned short* __restrict__ counts16,
                                   int* __restrict__ deg, int n) {
    int d = blockIdx.x * blockDim.x + threadIdx.x;
    if (d >= n) return;
    int c = d / RK_CH;
    int i = d - c * RK_CH;
    size_t base = ((size_t)c * RK_NS) * RK_CH + i;
    unsigned run = 0;
    for (int s = 0; s < RK_NS; ++s) {
        size_t idx = base + (size_t)s * RK_CH;
        unsigned v = counts16[idx];
        counts16[idx] = (unsigned short)run;
        run += v;
    }
    deg[d] = (int)run;
}

__global__ void scan1_kernel(const int* __restrict__ deg, int* __restrict__ rowptr,
                             int* __restrict__ bsum, int n) {
    __shared__ int s[1024];
    int lid = threadIdx.x;
    int i = blockIdx.x * 1024 + lid;
    int v = (i < n) ? deg[i] : 0;
    s[lid] = v;
    __syncthreads();
    #pragma unroll
    for (int off = 1; off < 1024; off <<= 1) {
        int t = (lid >= off) ? s[lid - off] : 0;
        __syncthreads();
        s[lid] += t;
        __syncthreads();
    }
    if (i < n) rowptr[i] = s[lid] - v;
    if (lid == 0) bsum[blockIdx.x] = s[1023];
}

__global__ void scan2_kernel(int* __restrict__ bsum, int nb) {
    __shared__ int s[1024];
    int lid = threadIdx.x;
    int v = (lid < nb) ? bsum[lid] : 0;
    s[lid] = v;
    __syncthreads();
    #pragma unroll
    for (int off = 1; off < 1024; off <<= 1) {
        int t = (lid >= off) ? s[lid - off] : 0;
        __syncthreads();
        s[lid] += t;
        __syncthreads();
    }
    if (lid < nb) bsum[lid] = s[lid] - v;
}

__global__ void scan3_kernel(int* __restrict__ rowptr, const int* __restrict__ bsum,
                             int n, int nE) {
    int i = blockIdx.x * blockDim.x + threadIdx.x;
    if (i < n) rowptr[i] += bsum[i >> 10];
    if (i == 0) rowptr[n] = nE;
}

// XCD-pinned scatter: block (c,s) with c = bid % cpad (cpad multiple of 8),
// so all blocks writing chunk c's esrc window share one XCD L2 -> sector
// writes coalesce. counts16 table for (c,s) is block-local (25KB).
__launch_bounds__(256)
__global__ void scatter3_kernel(const int* __restrict__ src, const int* __restrict__ dst,
                                const unsigned short* __restrict__ rank16,
                                const unsigned short* __restrict__ counts16,
                                const int* __restrict__ rowptr,
                                int* __restrict__ esrc, int nE, int nChunk, int cpad, int es) {
    int c = blockIdx.x % cpad;
    int s = blockIdx.x / cpad;
    if (c >= nChunk) return;
    int lo = c * RK_CH;
    const unsigned short* ctab = counts16 + ((size_t)(c * RK_NS + s)) * RK_CH;
    int ebeg = s * es;
    int eend = ebeg + es; if (eend > nE) eend = nE;
    if (ebeg >= eend) return;
    int nvec = (eend - ebeg) >> 2;   // es multiple of 4, bases 16B-aligned
    for (int g = threadIdx.x; g < nvec; g += 256) {
        int e = ebeg + g * 4;
        int4 d4 = *(const int4*)&dst[e];
        int4 s4 = *(const int4*)&src[e];
        ushort4 r4 = *(const ushort4*)&rank16[e];
        unsigned dc;
        dc = (unsigned)(d4.x - lo);
        if (dc < RK_CH) esrc[rowptr[lo + dc] + (int)ctab[dc] + (int)r4.x] = s4.x;
        dc = (unsigned)(d4.y - lo);
        if (dc < RK_CH) esrc[rowptr[lo + dc] + (int)ctab[dc] + (int)r4.y] = s4.y;
        dc = (unsigned)(d4.z - lo);
        if (dc < RK_CH) esrc[rowptr[lo + dc] + (int)ctab[dc] + (int)r4.z] = s4.z;
        dc = (unsigned)(d4.w - lo);
        if (dc < RK_CH) esrc[rowptr[lo + dc] + (int)ctab[dc] + (int)r4.w] = s4.w;
    }
    for (int e = ebeg + (nvec << 2) + threadIdx.x; e < eend; e += 256) {
        unsigned dc = (unsigned)(dst[e] - lo);
        if (dc < RK_CH) esrc[rowptr[lo + dc] + (int)ctab[dc] + (int)rank16[e]] = src[e];
    }
}

// ---------------- fp32 -> bf16 conversion ----------------

__global__ void cvt_kernel(const float* __restrict__ in, unsigned short* __restrict__ out, int n4) {
    int i = blockIdx.x * blockDim.x + threadIdx.x;
    if (i < n4) {
        float4 v = ((const float4*)in)[i];
        ushort4 o;
        o.x = f2bf(v.x); o.y = f2bf(v.y); o.z = f2bf(v.z); o.w = f2bf(v.w);
        ((ushort4*)out)[i] = o;
    }
}

__global__ void cvt6_kernel(const float* __restrict__ w0, const float* __restrict__ w1,
                            const float* __restrict__ w2, const float* __restrict__ w3,
                            const float* __restrict__ w4, const float* __restrict__ w5,
                            unsigned short* __restrict__ o0, unsigned short* __restrict__ o1,
                            unsigned short* __restrict__ o2, unsigned short* __restrict__ o3,
                            unsigned short* __restrict__ o4, unsigned short* __restrict__ o5,
                            int n4) {
    const float* in; unsigned short* out;
    switch (blockIdx.y) {
        case 0: in = w0; out = o0; break;
        case 1: in = w1; out = o1; break;
        case 2: in = w2; out = o2; break;
        case 3: in = w3; out = o3; break;
        case 4: in = w4; out = o4; break;
        default: in = w5; out = o5; break;
    }
    int i = blockIdx.x * blockDim.x + threadIdx.x;
    if (i < n4) {
        float4 v = ((const float4*)in)[i];
        ushort4 o;
        o.x = f2bf(v.x); o.y = f2bf(v.y); o.z = f2bf(v.z); o.w = f2bf(v.w);
        ((ushort4*)out)[i] = o;
    }
}

// ---------------- aggregation ----------------
// Quarter-wave per node (4 nodes/wave, 16 nodes/block). Lane li owns cols
// 8*li..8*li+8 and accumulates over ALL of its node's neighbors serially in
// registers — no cross-lane reduction. Row loads stay coalesced (16 lanes x
// 16B = 256B per row). Unroll-4 keeps 16 rows in flight per wave.

#define ACC8(v) do { \
    s0 += bf_lo((v).x); s1 += bf_hi((v).x); s2 += bf_lo((v).y); s3 += bf_hi((v).y); \
    s4 += bf_lo((v).z); s5 += bf_hi((v).z); s6 += bf_lo((v).w); s7 += bf_hi((v).w); } while (0)

__global__ void aggregate_kernel(const unsigned short* __restrict__ h,
                                 const int* __restrict__ rowptr,
                                 const int* __restrict__ esrc,
                                 unsigned short* __restrict__ agg, int n) {
    int wave = (blockIdx.x * blockDim.x + threadIdx.x) >> 6;
    int lane = threadIdx.x & 63;
    int q    = lane >> 4;           // which node within the wave
    int li   = lane & 15;
    int c0   = li * 8;              // 8 cols owned by this lane
    int node = wave * 4 + q;

    int beg = 0, end = 0;
    if (node < n) { beg = rowptr[node]; end = rowptr[node + 1]; }

    float s0=0.f,s1=0.f,s2=0.f,s3=0.f,s4=0.f,s5=0.f,s6=0.f,s7=0.f;
    int j = beg;
    for (; j + 4 <= end; j += 4) {
        int r0 = esrc[j], r1 = esrc[j + 1], r2 = esrc[j + 2], r3 = esrc[j + 3];
        uint4 v0 = *(const uint4*)&h[(size_t)r0 * 128 + c0];
        uint4 v1 = *(const uint4*)&h[(size_t)r1 * 128 + c0];
        uint4 v2 = *(const uint4*)&h[(size_t)r2 * 128 + c0];
        uint4 v3 = *(const uint4*)&h[(size_t)r3 * 128 + c0];
        ACC8(v0); ACC8(v1); ACC8(v2); ACC8(v3);
    }
    for (; j < end; ++j) {
        int r0 = esrc[j];
        uint4 v0 = *(const uint4*)&h[(size_t)r0 * 128 + c0];
        ACC8(v0);
    }
    if (node < n) {
        int cnt = end - beg;
        float inv = 1.0f / (float)(cnt > 1 ? cnt : 1);
        uint4 o;
        o.x = packbf(s0 * inv, s1 * inv);
        o.y = packbf(s2 * inv, s3 * inv);
        o.z = packbf(s4 * inv, s5 * inv);
        o.w = packbf(s6 * inv, s7 * inv);
        *(uint4*)&agg[(size_t)node * 128 + c0] = o;
    }
}

// ---------------- fused SAGE GEMM via MFMA ----------------

__launch_bounds__(256)
__global__ void sage_gemm_mfma(const unsigned short* __restrict__ A,
                               const unsigned short* __restrict__ H,
                               const unsigned short* __restrict__ Wl,
                               const unsigned short* __restrict__ Wr,
                               const float* __restrict__ bl,
                               unsigned short* __restrict__ out, int n, int relu) {
    int tid  = threadIdx.x;
    int lane = tid & 63;
    int w    = tid >> 6;
    int wm   = w >> 1, wn = w & 1;
    int br   = blockIdx.x * 128 + wm * 64;
    int bc   = wn * 64;
    int lrow = lane & 15;
    int lk   = (lane >> 4) * 8;

    f32x4 acc[4][4] = {};

    #pragma unroll
    for (int half = 0; half < 2; ++half) {
        const unsigned short* X = half ? H : A;
        const unsigned short* W = half ? Wr : Wl;
        const unsigned short* xp[4];
        const unsigned short* wp[4];
        #pragma unroll
        for (int mb = 0; mb < 4; ++mb) {
            int r = br + mb * 16 + lrow;
            if (r >= n) r = n - 1;
            xp[mb] = X + (size_t)r * 128 + lk;
        }
        #pragma unroll
        for (int nb = 0; nb < 4; ++nb)
            wp[nb] = W + (size_t)(bc + nb * 16 + lrow) * 128 + lk;

        #pragma unroll
        for (int ks = 0; ks < 4; ++ks) {
            short8v a[4], b[4];
            #pragma unroll
            for (int mb = 0; mb < 4; ++mb) a[mb] = *(const short8v*)(xp[mb] + ks * 32);
            #pragma unroll
            for (int nb = 0; nb < 4; ++nb) b[nb] = *(const short8v*)(wp[nb] + ks * 32);
            #pragma unroll
            for (int mb = 0; mb < 4; ++mb)
                #pragma unroll
                for (int nb = 0; nb < 4; ++nb)
                    acc[mb][nb] = __builtin_amdgcn_mfma_f32_16x16x32_bf16(
                        a[mb], b[nb], acc[mb][nb], 0, 0, 0);
        }
    }

    int ccol  = lane & 15;
    int crow4 = (lane >> 4) * 4;
    float bv[4];
    #pragma unroll
    for (int nb = 0; nb < 4; ++nb) bv[nb] = bl[bc + nb * 16 + ccol];

    #pragma unroll
    for (int mb = 0; mb < 4; ++mb) {
        #pragma unroll
        for (int r = 0; r < 4; ++r) {
            int row = br + mb * 16 + crow4 + r;
            if (row < n) {
                #pragma unroll
                for (int nb = 0; nb < 4; ++nb) {
                    int col = bc + nb * 16 + ccol;
                    float v = acc[mb][nb][r] + bv[nb];
                    if (relu && v < 0.f) v = 0.f;
                    out[(size_t)row * 128 + col] = f2bf(v);
                }
            }
        }
    }
}

// ---------------- pool + head ----------------

__device__ __forceinline__ int lbound(const int* __restrict__ a, int n, int v) {
    int lo = 0, hi = n;
    while (lo < hi) { int m = (lo + hi) >> 1; if (a[m] < v) lo = m + 1; else hi = m; }
    return lo;
}

__launch_bounds__(1024)
__global__ void pool_kernel(const unsigned short* __restrict__ h, const int* __restrict__ batch,
                            float* __restrict__ g, int n) {
    __shared__ float red[16][128];
    int b  = blockIdx.x;
    int rg = threadIdx.x >> 6;
    int cp = threadIdx.x & 63;
    int lo = lbound(batch, n, b);
    int hi = lbound(batch, n, b + 1);
    float s0 = 0.f, s1 = 0.f;
    for (int i = lo + rg; i < hi; i += 16) {
        unsigned v = *(const unsigned*)&h[(size_t)i * 128 + cp * 2];
        s0 += bf_lo(v); s1 += bf_hi(v);
    }
    red[rg][cp * 2]     = s0;
    red[rg][cp * 2 + 1] = s1;
    __syncthreads();
    #pragma unroll
    for (int off = 8; off >= 1; off >>= 1) {
        if (rg < off) {
            red[rg][cp * 2]     += red[rg + off][cp * 2];
            red[rg][cp * 2 + 1] += red[rg + off][cp * 2 + 1];
        }
        __syncthreads();
    }
    if (rg == 0) {
        int cnt = hi - lo;
        float inv = 1.0f / (float)(cnt > 1 ? cnt : 1);
        g[(size_t)b * 128 + cp * 2]     = red[0][cp * 2] * inv;
        g[(size_t)b * 128 + cp * 2 + 1] = red[0][cp * 2 + 1] * inv;
    }
}

__global__ void final_kernel(const float* __restrict__ g, const float* __restrict__ Wlin,
                             const float* __restrict__ blin, float* __restrict__ out, int total) {
    int gid = blockIdx.x * blockDim.x + threadIdx.x;
    if (gid >= total) return;
    int b = gid >> 5;
    int j = gid & 31;
    const float* gr = &g[(size_t)b * 128];
    const float* wr = &Wlin[(size_t)j * 128];
    float s = blin[j];
    #pragma unroll 4
    for (int c = 0; c < 128; ++c) s += gr[c] * wr[c];
    out[gid] = s;
}

extern "C" void kernel_launch(void* const* d_in, const int* in_sizes, int n_in,
                              void* d_out, int out_size, void* d_ws, size_t ws_size,
                              hipStream_t stream) {
    const float* x      = (const float*)d_in[0];
    const int*   eidx   = (const int*)d_in[1];
    const int*   batch  = (const int*)d_in[2];
    const float* Wl[3]  = {(const float*)d_in[3], (const float*)d_in[6], (const float*)d_in[9]};
    const float* bl[3]  = {(const float*)d_in[4], (const float*)d_in[7], (const float*)d_in[10]};
    const float* Wr[3]  = {(const float*)d_in[5], (const float*)d_in[8], (const float*)d_in[11]};
    const float* Wlin   = (const float*)d_in[12];
    const float* blin   = (const float*)d_in[13];
    float* out = (float*)d_out;

    const int N = in_sizes[0] / 128;
    const int E = in_sizes[1] / 2;
    const int G = out_size / 32;

    const int* esrc_in = eidx;
    const int* edst_in = eidx + E;

    char* w = (char*)d_ws;
    auto carve = [&](size_t bytes) { char* p = w; w += (bytes + 255) & ~(size_t)255; return p; };
    unsigned short* xbf  = (unsigned short*)carve((size_t)N * 128 * 2);
    unsigned short* hA   = (unsigned short*)carve((size_t)N * 128 * 2);
    unsigned short* hB   = (unsigned short*)carve((size_t)N * 128 * 2);
    unsigned short* agg  = (unsigned short*)carve((size_t)N * 128 * 2);
    unsigned short* Wbf[6];
    for (int i = 0; i < 6; ++i) Wbf[i] = (unsigned short*)carve((size_t)128 * 128 * 2);
    float* g      = (float*)carve((size_t)G * 128 * 4);
    int*   deg    = (int*)carve((size_t)N * 4);
    int*   rowptr = (int*)carve((size_t)(N + 1) * 4);
    int*   bsum   = (int*)carve(1024 * 4);
    int*   esrc   = (int*)carve((size_t)E * 4);
    unsigned short* rank16   = (unsigned short*)carve((size_t)E * 2);
    int nChunk = (N + RK_CH - 1) / RK_CH;
    unsigned short* counts16 = (unsigned short*)carve((size_t)nChunk * RK_NS * RK_CH * 2);
    (void)ws_size; (void)n_in;

    // --- CSR build: LDS-histogram rank (no global atomics), scan, XCD-pinned scatter ---
    int es = (((E + RK_NS - 1) / RK_NS) + 3) & ~3;   // slice size, multiple of 4
    hipLaunchKernelGGL(rank_hist_kernel, dim3(nChunk * RK_NS), dim3(256), 0, stream,
                       edst_in, rank16, counts16, E, nChunk, es);
    int ngrid = (N + 255) / 256;
    hipLaunchKernelGGL(seg_offsets_kernel, dim3(ngrid), dim3(256), 0, stream,
                       counts16, deg, N);
    int nchunks = (N + 1023) / 1024;
    hipLaunchKernelGGL(scan1_kernel, dim3(nchunks), dim3(1024), 0, stream, deg, rowptr, bsum, N);
    hipLaunchKernelGGL(scan2_kernel, dim3(1), dim3(1024), 0, stream, bsum, nchunks);
    hipLaunchKernelGGL(scan3_kernel, dim3(ngrid), dim3(256), 0, stream, rowptr, bsum, N, E);
    int cpad = (nChunk + 7) & ~7;   // multiple of 8 so bid%cpad preserves bid%8 per chunk
    hipLaunchKernelGGL(scatter3_kernel, dim3(RK_NS * cpad), dim3(256), 0, stream,
                       esrc_in, edst_in, rank16, counts16, rowptr, esrc, E, nChunk, cpad, es);

    // --- bf16 conversions ---
    int x4 = N * 128 / 4;
    hipLaunchKernelGGL(cvt_kernel, dim3((x4 + 255) / 256), dim3(256), 0, stream, x, xbf, x4);
    int w4 = 128 * 128 / 4;
    hipLaunchKernelGGL(cvt6_kernel, dim3((w4 + 255) / 256, 6), dim3(256), 0, stream,
                       Wl[0], Wr[0], Wl[1], Wr[1], Wl[2], Wr[2],
                       Wbf[0], Wbf[1], Wbf[2], Wbf[3], Wbf[4], Wbf[5], w4);

    // --- 3 SAGE layers ---
    int agrid = (N + 15) / 16;   // 16 nodes per 256-thread block (4 per wave)
    int ggrid = (N + 127) / 128;
    const unsigned short* hin = xbf;
    unsigned short* houts[3] = {hA, hB, hA};
    for (int l = 0; l < 3; ++l) {
        hipLaunchKernelGGL(aggregate_kernel, dim3(agrid), dim3(256), 0, stream,
                           hin, rowptr, esrc, agg, N);
        hipLaunchKernelGGL(sage_gemm_mfma, dim3(ggrid), dim3(256), 0, stream,
                           agg, hin, Wbf[2*l], Wbf[2*l+1], bl[l], houts[l], N, (l < 2) ? 1 : 0);
        hin = houts[l];
    }

    // --- pool + head ---
    hipLaunchKernelGGL(pool_kernel, dim3(G), dim3(1024), 0, stream, hin, batch, g, N);
    int fgrid = (out_size + 255) / 256;
    hipLaunchKernelGGL(final_kernel, dim3(fgrid), dim3(256), 0, stream, g, Wlin, blin, out, out_size);
}

// Round 8
// 382.798 us; speedup vs baseline: 1.0615x; 1.0615x over previous
//
#include <hip/hip_runtime.h>
#include <hip/hip_bf16.h>

// ---------------------------------------------------------------------------
// GraphSAGE forward on MI355X — round 11.
// Post-mortems:
//  * r9/r10: aggregate is AT its structural floor (~176MB L3 traffic = 8 XCDs
//    x 86% coverage of h; 57.5us at ~3.5TB/s service). scatter3's 8x re-scan
//    cost more than the write amplification it removed. Reverted to r8 CSR.
// Changes vs round 8 (best, 391.7us):
//  * pre_kernel: rank_hist + cvt(x) + cvt6(weights) horizontally fused into
//    one dispatch (blockIdx-partitioned) — conversions hide under the
//    LDS/latency-bound histogram instead of running serially.
//  * seg_offsets + scan1 merged (seg_scan1, 1024 thr; deg buffer gone).
//  * final_kernel folded into pool_kernel (g buffer gone).
//  16 dispatches -> 11.
// ---------------------------------------------------------------------------

typedef __attribute__((ext_vector_type(8))) short short8v;   // 8 x bf16 (4 VGPRs)
typedef __attribute__((ext_vector_type(4))) float f32x4;

#define RK_CH 12544   // nodes per dst-chunk (50,176 B LDS histogram)
#define RK_NS 64      // edge slices

__device__ __forceinline__ unsigned short f2bf(float f) {
    __hip_bfloat16 h = __float2bfloat16(f);
    return *reinterpret_cast<unsigned short*>(&h);
}
__device__ __forceinline__ float bf_lo(unsigned u) { return __uint_as_float(u << 16); }
__device__ __forceinline__ float bf_hi(unsigned u) { return __uint_as_float(u & 0xffff0000u); }
__device__ __forceinline__ unsigned packbf(float lo, float hi) {
    return ((unsigned)f2bf(hi) << 16) | f2bf(lo);
}

// ---------------- fused pre-pass: rank_hist | cvt(x) | cvt6(weights) -------
// Blocks [0, rhB)              : LDS-histogram rank (chunk c, slice s)
// Blocks [rhB, rhB+cvtB)       : x fp32 -> bf16
// Blocks [rhB+cvtB, +6*w4b)    : 6 weight matrices fp32 -> bf16

__launch_bounds__(256)
__global__ void pre_kernel(const int* __restrict__ dst,
                           unsigned short* __restrict__ rank16,
                           unsigned short* __restrict__ counts16,
                           int nE, int nChunk, int es,
                           const float* __restrict__ x, unsigned short* __restrict__ xbf, int x4,
                           const float* __restrict__ w0, const float* __restrict__ w1,
                           const float* __restrict__ w2, const float* __restrict__ w3,
                           const float* __restrict__ w4, const float* __restrict__ w5,
                           unsigned short* __restrict__ o0, unsigned short* __restrict__ o1,
                           unsigned short* __restrict__ o2, unsigned short* __restrict__ o3,
                           unsigned short* __restrict__ o4, unsigned short* __restrict__ o5,
                           int w4n, int w4b) {
    __shared__ unsigned cnt[RK_CH];
    int rhB  = nChunk * RK_NS;
    int cvtB = (x4 + 255) / 256;
    int bid  = blockIdx.x;

    if (bid < rhB) {
        // ---- rank_hist ----
        int s = bid / nChunk;   // consecutive blocks share the dst slice
        int c = bid % nChunk;
        int lo = c * RK_CH;
        for (int i = threadIdx.x; i < RK_CH; i += 256) cnt[i] = 0u;
        __syncthreads();

        int ebeg = s * es;
        int eend = ebeg + es; if (eend > nE) eend = nE;
        if (ebeg < eend) {
            int nvec = (eend - ebeg) >> 2;   // es multiple of 4, dst 16B-aligned
            for (int g = threadIdx.x; g < nvec; g += 256) {
                int e = ebeg + g * 4;
                int4 d4 = *(const int4*)&dst[e];
                unsigned dc;
                dc = (unsigned)(d4.x - lo);
                if (dc < RK_CH) rank16[e]     = (unsigned short)atomicAdd(&cnt[dc], 1u);
                dc = (unsigned)(d4.y - lo);
                if (dc < RK_CH) rank16[e + 1] = (unsigned short)atomicAdd(&cnt[dc], 1u);
                dc = (unsigned)(d4.z - lo);
                if (dc < RK_CH) rank16[e + 2] = (unsigned short)atomicAdd(&cnt[dc], 1u);
                dc = (unsigned)(d4.w - lo);
                if (dc < RK_CH) rank16[e + 3] = (unsigned short)atomicAdd(&cnt[dc], 1u);
            }
            for (int e = ebeg + (nvec << 2) + threadIdx.x; e < eend; e += 256) {
                unsigned dc = (unsigned)(dst[e] - lo);
                if (dc < RK_CH) rank16[e] = (unsigned short)atomicAdd(&cnt[dc], 1u);
            }
        }
        __syncthreads();
        size_t base = ((size_t)(c * RK_NS + s)) * RK_CH;
        for (int i = threadIdx.x; i < RK_CH; i += 256)
            counts16[base + i] = (unsigned short)cnt[i];
    } else if (bid < rhB + cvtB) {
        // ---- cvt x ----
        int i = (bid - rhB) * 256 + threadIdx.x;
        if (i < x4) {
            float4 v = ((const float4*)x)[i];
            ushort4 o;
            o.x = f2bf(v.x); o.y = f2bf(v.y); o.z = f2bf(v.z); o.w = f2bf(v.w);
            ((ushort4*)xbf)[i] = o;
        }
    } else {
        // ---- cvt6 weights ----
        int idx  = bid - rhB - cvtB;
        int wsel = idx / w4b;
        int wb   = idx % w4b;
        const float* in; unsigned short* out;
        switch (wsel) {
            case 0: in = w0; out = o0; break;
            case 1: in = w1; out = o1; break;
            case 2: in = w2; out = o2; break;
            case 3: in = w3; out = o3; break;
            case 4: in = w4; out = o4; break;
            default: in = w5; out = o5; break;
        }
        int i = wb * 256 + threadIdx.x;
        if (i < w4n) {
            float4 v = ((const float4*)in)[i];
            ushort4 o;
            o.x = f2bf(v.x); o.y = f2bf(v.y); o.z = f2bf(v.z); o.w = f2bf(v.w);
            ((ushort4*)out)[i] = o;
        }
    }
}

// ---------------- seg_offsets + scan1 fused ----------------
// Thread d: exclusive scan over its RK_NS slice counts (in place) -> deg,
// then block-level scan over 1024 degs -> rowptr partial + bsum.

__launch_bounds__(1024)
__global__ void seg_scan1_kernel(unsigned short* __restrict__ counts16,
                                 int* __restrict__ rowptr, int* __restrict__ bsum, int n) {
    __shared__ int s[1024];
    int lid = threadIdx.x;
    int d = blockIdx.x * 1024 + lid;
    int v = 0;
    if (d < n) {
        int c = d / RK_CH;
        int i = d - c * RK_CH;
        size_t base = ((size_t)c * RK_NS) * RK_CH + i;
        unsigned run = 0;
        for (int sl = 0; sl < RK_NS; ++sl) {
            size_t idx = base + (size_t)sl * RK_CH;
            unsigned t = counts16[idx];
            counts16[idx] = (unsigned short)run;
            run += t;
        }
        v = (int)run;
    }
    s[lid] = v;
    __syncthreads();
    #pragma unroll
    for (int off = 1; off < 1024; off <<= 1) {
        int t = (lid >= off) ? s[lid - off] : 0;
        __syncthreads();
        s[lid] += t;
        __syncthreads();
    }
    if (d < n) rowptr[d] = s[lid] - v;
    if (lid == 0) bsum[blockIdx.x] = s[1023];
}

__global__ void scan2_kernel(int* __restrict__ bsum, int nb) {
    __shared__ int s[1024];
    int lid = threadIdx.x;
    int v = (lid < nb) ? bsum[lid] : 0;
    s[lid] = v;
    __syncthreads();
    #pragma unroll
    for (int off = 1; off < 1024; off <<= 1) {
        int t = (lid >= off) ? s[lid - off] : 0;
        __syncthreads();
        s[lid] += t;
        __syncthreads();
    }
    if (lid < nb) bsum[lid] = s[lid] - v;
}

__global__ void scan3_kernel(int* __restrict__ rowptr, const int* __restrict__ bsum,
                             int n, int nE) {
    int i = blockIdx.x * blockDim.x + threadIdx.x;
    if (i < n) rowptr[i] += bsum[i >> 10];
    if (i == 0) rowptr[n] = nE;
}

__global__ void scatter2_kernel(const int* __restrict__ src, const int* __restrict__ dst,
                                const unsigned short* __restrict__ rank16,
                                const unsigned short* __restrict__ counts16,
                                const int* __restrict__ rowptr,
                                int* __restrict__ esrc, int nE, int es) {
    int e = blockIdx.x * blockDim.x + threadIdx.x;
    if (e >= nE) return;
    int d = dst[e];
    int s = e / es;
    int c = d / RK_CH;
    int i = d - c * RK_CH;
    int pos = rowptr[d] + (int)counts16[((size_t)(c * RK_NS + s)) * RK_CH + i]
                        + (int)rank16[e];
    esrc[pos] = src[e];
}

// ---------------- aggregation ----------------
// Quarter-wave per node (4 nodes/wave, 16 nodes/block). Lane li owns cols
// 8*li..8*li+8 and accumulates over ALL of its node's neighbors serially in
// registers — no cross-lane reduction. Row loads stay coalesced (16 lanes x
// 16B = 256B per row). Unroll-4 keeps 16 rows in flight per wave.
// NOTE (r9/r10): this kernel is at its structural floor — 8 XCDs each fetch
// ~86% of h's lines (178MB L3 traffic) at ~3.5TB/s service. Do not re-tune.

#define ACC8(v) do { \
    s0 += bf_lo((v).x); s1 += bf_hi((v).x); s2 += bf_lo((v).y); s3 += bf_hi((v).y); \
    s4 += bf_lo((v).z); s5 += bf_hi((v).z); s6 += bf_lo((v).w); s7 += bf_hi((v).w); } while (0)

__global__ void aggregate_kernel(const unsigned short* __restrict__ h,
                                 const int* __restrict__ rowptr,
                                 const int* __restrict__ esrc,
                                 unsigned short* __restrict__ agg, int n) {
    int wave = (blockIdx.x * blockDim.x + threadIdx.x) >> 6;
    int lane = threadIdx.x & 63;
    int q    = lane >> 4;           // which node within the wave
    int li   = lane & 15;
    int c0   = li * 8;              // 8 cols owned by this lane
    int node = wave * 4 + q;

    int beg = 0, end = 0;
    if (node < n) { beg = rowptr[node]; end = rowptr[node + 1]; }

    float s0=0.f,s1=0.f,s2=0.f,s3=0.f,s4=0.f,s5=0.f,s6=0.f,s7=0.f;
    int j = beg;
    for (; j + 4 <= end; j += 4) {
        int r0 = esrc[j], r1 = esrc[j + 1], r2 = esrc[j + 2], r3 = esrc[j + 3];
        uint4 v0 = *(const uint4*)&h[(size_t)r0 * 128 + c0];
        uint4 v1 = *(const uint4*)&h[(size_t)r1 * 128 + c0];
        uint4 v2 = *(const uint4*)&h[(size_t)r2 * 128 + c0];
        uint4 v3 = *(const uint4*)&h[(size_t)r3 * 128 + c0];
        ACC8(v0); ACC8(v1); ACC8(v2); ACC8(v3);
    }
    for (; j < end; ++j) {
        int r0 = esrc[j];
        uint4 v0 = *(const uint4*)&h[(size_t)r0 * 128 + c0];
        ACC8(v0);
    }
    if (node < n) {
        int cnt = end - beg;
        float inv = 1.0f / (float)(cnt > 1 ? cnt : 1);
        uint4 o;
        o.x = packbf(s0 * inv, s1 * inv);
        o.y = packbf(s2 * inv, s3 * inv);
        o.z = packbf(s4 * inv, s5 * inv);
        o.w = packbf(s6 * inv, s7 * inv);
        *(uint4*)&agg[(size_t)node * 128 + c0] = o;
    }
}

// ---------------- fused SAGE GEMM via MFMA ----------------

__launch_bounds__(256)
__global__ void sage_gemm_mfma(const unsigned short* __restrict__ A,
                               const unsigned short* __restrict__ H,
                               const unsigned short* __restrict__ Wl,
                               const unsigned short* __restrict__ Wr,
                               const float* __restrict__ bl,
                               unsigned short* __restrict__ out, int n, int relu) {
    int tid  = threadIdx.x;
    int lane = tid & 63;
    int w    = tid >> 6;
    int wm   = w >> 1, wn = w & 1;
    int br   = blockIdx.x * 128 + wm * 64;
    int bc   = wn * 64;
    int lrow = lane & 15;
    int lk   = (lane >> 4) * 8;

    f32x4 acc[4][4] = {};

    #pragma unroll
    for (int half = 0; half < 2; ++half) {
        const unsigned short* X = half ? H : A;
        const unsigned short* W = half ? Wr : Wl;
        const unsigned short* xp[4];
        const unsigned short* wp[4];
        #pragma unroll
        for (int mb = 0; mb < 4; ++mb) {
            int r = br + mb * 16 + lrow;
            if (r >= n) r = n - 1;
            xp[mb] = X + (size_t)r * 128 + lk;
        }
        #pragma unroll
        for (int nb = 0; nb < 4; ++nb)
            wp[nb] = W + (size_t)(bc + nb * 16 + lrow) * 128 + lk;

        #pragma unroll
        for (int ks = 0; ks < 4; ++ks) {
            short8v a[4], b[4];
            #pragma unroll
            for (int mb = 0; mb < 4; ++mb) a[mb] = *(const short8v*)(xp[mb] + ks * 32);
            #pragma unroll
            for (int nb = 0; nb < 4; ++nb) b[nb] = *(const short8v*)(wp[nb] + ks * 32);
            #pragma unroll
            for (int mb = 0; mb < 4; ++mb)
                #pragma unroll
                for (int nb = 0; nb < 4; ++nb)
                    acc[mb][nb] = __builtin_amdgcn_mfma_f32_16x16x32_bf16(
                        a[mb], b[nb], acc[mb][nb], 0, 0, 0);
        }
    }

    int ccol  = lane & 15;
    int crow4 = (lane >> 4) * 4;
    float bv[4];
    #pragma unroll
    for (int nb = 0; nb < 4; ++nb) bv[nb] = bl[bc + nb * 16 + ccol];

    #pragma unroll
    for (int mb = 0; mb < 4; ++mb) {
        #pragma unroll
        for (int r = 0; r < 4; ++r) {
            int row = br + mb * 16 + crow4 + r;
            if (row < n) {
                #pragma unroll
                for (int nb = 0; nb < 4; ++nb) {
                    int col = bc + nb * 16 + ccol;
                    float v = acc[mb][nb][r] + bv[nb];
                    if (relu && v < 0.f) v = 0.f;
                    out[(size_t)row * 128 + col] = f2bf(v);
                }
            }
        }
    }
}

// ---------------- pool + head (fused) ----------------

__device__ __forceinline__ int lbound(const int* __restrict__ a, int n, int v) {
    int lo = 0, hi = n;
    while (lo < hi) { int m = (lo + hi) >> 1; if (a[m] < v) lo = m + 1; else hi = m; }
    return lo;
}

// One block (1024 thr = 16 waves) per graph. Wave rg sums rows lo+rg,
// lo+rg+16, ...; lane covers 2 cols. LDS tree reduce 16 -> 1, then wave 0
// computes the 32 class outputs directly (head fused; no g buffer).
__launch_bounds__(1024)
__global__ void pool_head_kernel(const unsigned short* __restrict__ h,
                                 const int* __restrict__ batch,
                                 const float* __restrict__ Wlin,
                                 const float* __restrict__ blin,
                                 float* __restrict__ out, int n) {
    __shared__ float red[16][128];
    int b  = blockIdx.x;
    int rg = threadIdx.x >> 6;
    int cp = threadIdx.x & 63;
    int lo = lbound(batch, n, b);
    int hi = lbound(batch, n, b + 1);
    float s0 = 0.f, s1 = 0.f;
    for (int i = lo + rg; i < hi; i += 16) {
        unsigned v = *(const unsigned*)&h[(size_t)i * 128 + cp * 2];
        s0 += bf_lo(v); s1 += bf_hi(v);
    }
    red[rg][cp * 2]     = s0;
    red[rg][cp * 2 + 1] = s1;
    __syncthreads();
    #pragma unroll
    for (int off = 8; off >= 1; off >>= 1) {
        if (rg < off) {
            red[rg][cp * 2]     += red[rg + off][cp * 2];
            red[rg][cp * 2 + 1] += red[rg + off][cp * 2 + 1];
        }
        __syncthreads();
    }
    if (threadIdx.x < 32) {
        int j = threadIdx.x;
        int cnt = hi - lo;
        float inv = 1.0f / (float)(cnt > 1 ? cnt : 1);
        const float* wr = &Wlin[(size_t)j * 128];
        float s = 0.f;
        #pragma unroll 4
        for (int c = 0; c < 128; ++c) s += red[0][c] * wr[c];
        out[(size_t)b * 32 + j] = blin[j] + s * inv;
    }
}

extern "C" void kernel_launch(void* const* d_in, const int* in_sizes, int n_in,
                              void* d_out, int out_size, void* d_ws, size_t ws_size,
                              hipStream_t stream) {
    const float* x      = (const float*)d_in[0];
    const int*   eidx   = (const int*)d_in[1];
    const int*   batch  = (const int*)d_in[2];
    const float* Wl[3]  = {(const float*)d_in[3], (const float*)d_in[6], (const float*)d_in[9]};
    const float* bl[3]  = {(const float*)d_in[4], (const float*)d_in[7], (const float*)d_in[10]};
    const float* Wr[3]  = {(const float*)d_in[5], (const float*)d_in[8], (const float*)d_in[11]};
    const float* Wlin   = (const float*)d_in[12];
    const float* blin   = (const float*)d_in[13];
    float* out = (float*)d_out;

    const int N = in_sizes[0] / 128;
    const int E = in_sizes[1] / 2;

    const int* esrc_in = eidx;
    const int* edst_in = eidx + E;

    char* w = (char*)d_ws;
    auto carve = [&](size_t bytes) { char* p = w; w += (bytes + 255) & ~(size_t)255; return p; };
    unsigned short* xbf  = (unsigned short*)carve((size_t)N * 128 * 2);
    unsigned short* hA   = (unsigned short*)carve((size_t)N * 128 * 2);
    unsigned short* hB   = (unsigned short*)carve((size_t)N * 128 * 2);
    unsigned short* agg  = (unsigned short*)carve((size_t)N * 128 * 2);
    unsigned short* Wbf[6];
    for (int i = 0; i < 6; ++i) Wbf[i] = (unsigned short*)carve((size_t)128 * 128 * 2);
    int*   rowptr = (int*)carve((size_t)(N + 1) * 4);
    int*   bsum   = (int*)carve(1024 * 4);
    int*   esrc   = (int*)carve((size_t)E * 4);
    unsigned short* rank16   = (unsigned short*)carve((size_t)E * 2);
    int nChunk = (N + RK_CH - 1) / RK_CH;
    unsigned short* counts16 = (unsigned short*)carve((size_t)nChunk * RK_NS * RK_CH * 2);
    (void)ws_size; (void)n_in;

    // --- fused pre-pass: rank_hist | cvt x | cvt weights ---
    int es = (((E + RK_NS - 1) / RK_NS) + 3) & ~3;   // slice size, multiple of 4
    int x4   = N * 128 / 4;
    int cvtB = (x4 + 255) / 256;
    int w4n  = 128 * 128 / 4;
    int w4b  = (w4n + 255) / 256;
    int rhB  = nChunk * RK_NS;
    hipLaunchKernelGGL(pre_kernel, dim3(rhB + cvtB + 6 * w4b), dim3(256), 0, stream,
                       edst_in, rank16, counts16, E, nChunk, es,
                       x, xbf, x4,
                       Wl[0], Wr[0], Wl[1], Wr[1], Wl[2], Wr[2],
                       Wbf[0], Wbf[1], Wbf[2], Wbf[3], Wbf[4], Wbf[5],
                       w4n, w4b);

    // --- offsets + scans + scatter ---
    int nchunks = (N + 1023) / 1024;
    hipLaunchKernelGGL(seg_scan1_kernel, dim3(nchunks), dim3(1024), 0, stream,
                       counts16, rowptr, bsum, N);
    hipLaunchKernelGGL(scan2_kernel, dim3(1), dim3(1024), 0, stream, bsum, nchunks);
    int ngrid = (N + 255) / 256;
    hipLaunchKernelGGL(scan3_kernel, dim3(ngrid), dim3(256), 0, stream, rowptr, bsum, N, E);
    int egrid = (E + 255) / 256;
    hipLaunchKernelGGL(scatter2_kernel, dim3(egrid), dim3(256), 0, stream,
                       esrc_in, edst_in, rank16, counts16, rowptr, esrc, E, es);

    // --- 3 SAGE layers ---
    int agrid = (N + 15) / 16;   // 16 nodes per 256-thread block (4 per wave)
    int ggrid = (N + 127) / 128;
    const unsigned short* hin = xbf;
    unsigned short* houts[3] = {hA, hB, hA};
    for (int l = 0; l < 3; ++l) {
        hipLaunchKernelGGL(aggregate_kernel, dim3(agrid), dim3(256), 0, stream,
                           hin, rowptr, esrc, agg, N);
        hipLaunchKernelGGL(sage_gemm_mfma, dim3(ggrid), dim3(256), 0, stream,
                           agg, hin, Wbf[2*l], Wbf[2*l+1], bl[l], houts[l], N, (l < 2) ? 1 : 0);
        hin = houts[l];
    }

    // --- pool + head (fused) ---
    int G = out_size / 32;
    hipLaunchKernelGGL(pool_head_kernel, dim3(G), dim3(1024), 0, stream,
                       hin, batch, Wlin, blin, out, N);
}